// Round 2
// baseline (3844.106 us; speedup 1.0000x reference)
//
#include <hip/hip_runtime.h>
#include <cstddef>

// Problem constants
constexpr int Nf  = 128;                 // frames (i/I)
constexpr int Pp  = 256;                 // points (j/J)
constexpr int Dd  = 256;
constexpr int Hh  = 16;
constexpr int Mm  = 32;
constexpr int OUTC = 512;                // H*M
constexpr int HID  = 2048;
constexpr int C3   = 3 * OUTC;           // 1536 (w,h,m) columns

// ---------------------------------------------------------------------------
// Repack small weight tensors into row-major GEMM B matrices.
// B1[d][c] with c = w*512 + h*32 + m   (256 x 1536)
__global__ void repack_b1(const float* __restrict__ Wt, float* __restrict__ B1) {
  int idx = blockIdx.x * 256 + threadIdx.x;   // 393216 total
  int d = idx / C3, c = idx % C3;
  int w = c >> 9, h = (c >> 5) & 15, m = c & 31;
  B1[idx] = Wt[((w * Dd + d) * Hh + h) * Mm + m];
}

// B2[k][c] with k = H*32 + M (contraction over temporal's (H,M)), c = w*512+h*32+m
__global__ void repack_b2(const float* __restrict__ Wp, float* __restrict__ B2) {
  int idx = blockIdx.x * 256 + threadIdx.x;   // 786432 total
  int k = idx / C3, c = idx % C3;
  int w = c >> 9, h = (c >> 5) & 15, m = c & 31;
  int HH = k >> 5, MM = k & 31;
  B2[idx] = Wp[(((w * Hh + h) * Mm + m) * Hh + HH) * Mm + MM];
}

// ---------------------------------------------------------------------------
// Shared fp32 tiled GEMM: C(128x128 tile) = A(128xK) @ B(Kx128) [+bias]
// AMAP=0: A row rr is literal. AMAP=1: rr = i*JC+jj -> x row i*256 + j0 + jj.
// EPI=0: plain row-major + bias.
// EPI=1: scatter to (w,h,jj,i,m) chunk layout (pc = JC, pshift = log2 JC).
// EPI=2: scatter to (w,h,ii,j,m) chunk layout (pc = IC), rows rr = ii*256+j.
template <int KDIM, int NCOLS, int AMAP, int EPI>
__global__ __launch_bounds__(256) void gemm128(const float* __restrict__ A,
                                               const float* __restrict__ B,
                                               float* __restrict__ C,
                                               const float* __restrict__ bias,
                                               int j0, int pshift, int pc) {
  __shared__ __align__(16) float As[16][132];   // transposed A tile, padded
  __shared__ __align__(16) float Bs[16][128];
  const int t = threadIdx.x;
  const int tx = t & 15, ty = t >> 4;
  const int row0 = blockIdx.y * 128;
  const int col0 = blockIdx.x * 128;

  float acc[8][8];
#pragma unroll
  for (int i = 0; i < 8; ++i)
#pragma unroll
    for (int j = 0; j < 8; ++j) acc[i][j] = 0.f;

  for (int kt = 0; kt < KDIM; kt += 16) {
#pragma unroll
    for (int u = 0; u < 2; ++u) {
      int idx = t + u * 256;
      int r = idx >> 2, c4 = (idx & 3) * 4;
      int rr = row0 + r;
      size_t arow;
      if (AMAP == 0) {
        arow = (size_t)rr;
      } else {
        int i = rr >> pshift, jj = rr & (pc - 1);
        arow = (size_t)((i << 8) + j0 + jj);
      }
      float4 av = *(const float4*)(A + arow * KDIM + kt + c4);
      As[c4 + 0][r] = av.x;
      As[c4 + 1][r] = av.y;
      As[c4 + 2][r] = av.z;
      As[c4 + 3][r] = av.w;
    }
#pragma unroll
    for (int u = 0; u < 2; ++u) {
      int idx = t + u * 256;
      int k = idx >> 5, c4 = (idx & 31) * 4;
      *(float4*)&Bs[k][c4] = *(const float4*)(B + (size_t)(kt + k) * NCOLS + col0 + c4);
    }
    __syncthreads();
#pragma unroll
    for (int kk = 0; kk < 16; ++kk) {
      float a[8], b[8];
      *(float4*)&a[0] = *(const float4*)&As[kk][ty * 4];
      *(float4*)&a[4] = *(const float4*)&As[kk][64 + ty * 4];
      *(float4*)&b[0] = *(const float4*)&Bs[kk][tx * 4];
      *(float4*)&b[4] = *(const float4*)&Bs[kk][64 + tx * 4];
#pragma unroll
      for (int i = 0; i < 8; ++i)
#pragma unroll
        for (int j = 0; j < 8; ++j) acc[i][j] += a[i] * b[j];
    }
    __syncthreads();
  }

#pragma unroll
  for (int i = 0; i < 8; ++i) {
    int r = row0 + ((i & 4) ? 64 : 0) + ty * 4 + (i & 3);
#pragma unroll
    for (int jh = 0; jh < 2; ++jh) {
      int c = col0 + (jh ? 64 : 0) + tx * 4;
      float4 v;
      v.x = acc[i][jh * 4 + 0];
      v.y = acc[i][jh * 4 + 1];
      v.z = acc[i][jh * 4 + 2];
      v.w = acc[i][jh * 4 + 3];
      if (EPI == 0) {
        float4 bv = *(const float4*)(bias + c);
        v.x += bv.x; v.y += bv.y; v.z += bv.z; v.w += bv.w;
        *(float4*)(C + (size_t)r * NCOLS + c) = v;
      } else {
        int w = c >> 9, h = (c >> 5) & 15, m = c & 31;
        size_t addr;
        if (EPI == 1) {
          int ii = r >> pshift, jj = r & (pc - 1);
          addr = (((size_t)(w * Hh + h) * pc + jj) * Nf + ii) * Mm + m;
        } else {
          int ii = r >> 8, jj = r & 255;
          addr = (((size_t)(w * Hh + h) * pc + ii) * Pp + jj) * Mm + m;
        }
        *(float4*)(C + addr) = v;
      }
    }
  }
}

// ---------------------------------------------------------------------------
// Temporal attention (transposed form per the reference einsum):
//   S[a][b] = q_a . k_b ; W = rowsoftmax(S) ; out[i] = sum_I W[I][i] * v[I]
// One block per (h, jj in chunk); 128 threads. T is the (w,h,jj,i,m) chunk.
__global__ __launch_bounds__(128) void temporal_attn(const float* __restrict__ T,
                                                     float* __restrict__ At,
                                                     int j0, int jcShift) {
  const int JC = 1 << jcShift;
  const int h  = blockIdx.x >> jcShift;
  const int jj = blockIdx.x & (JC - 1);
  const int t  = threadIdx.x;
  __shared__ __align__(16) float Qs[Nf * Mm];
  __shared__ __align__(16) float Ks[Nf * Mm];
  __shared__ __align__(16) float Vs[Nf * Mm];
  __shared__ float inv[Nf];
  const size_t WC = (size_t)(Hh << jcShift) * (Nf * Mm);
  const float* qb = T + (size_t)(h * JC + jj) * (Nf * Mm);
  const float* kb = qb + WC;
  const float* vb = qb + 2 * WC;
#pragma unroll
  for (int u = 0; u < 8; ++u) {
    int idx = t + u * 128;
    ((float4*)Qs)[idx] = ((const float4*)qb)[idx];
    ((float4*)Ks)[idx] = ((const float4*)kb)[idx];
    ((float4*)Vs)[idx] = ((const float4*)vb)[idx];
  }
  __syncthreads();

  // Pass A: thread a computes rowsum_a = sum_b exp(q_a . k_b). Scores are O(1),
  // so exp without max-subtraction is safe in fp32.
  float q[32];
#pragma unroll
  for (int m4 = 0; m4 < 8; ++m4) *(float4*)&q[m4 * 4] = *(const float4*)&Qs[t * 32 + m4 * 4];
  float ssum = 0.f;
  for (int b = 0; b < Nf; ++b) {
    const float4* kr = (const float4*)&Ks[b * 32];
    float s = 0.f;
#pragma unroll
    for (int m4 = 0; m4 < 8; ++m4) {
      float4 kv = kr[m4];
      s += q[m4 * 4 + 0] * kv.x + q[m4 * 4 + 1] * kv.y +
           q[m4 * 4 + 2] * kv.z + q[m4 * 4 + 3] * kv.w;
    }
    ssum += __expf(s);
  }
  inv[t] = 1.f / ssum;
  __syncthreads();

  // Pass B: thread i gathers column i: out[i][m] = sum_I exp(q_I.k_i)*inv[I]*V[I][m]
  float kreg[32];
#pragma unroll
  for (int m4 = 0; m4 < 8; ++m4) *(float4*)&kreg[m4 * 4] = *(const float4*)&Ks[t * 32 + m4 * 4];
  float o[32];
#pragma unroll
  for (int m = 0; m < 32; ++m) o[m] = 0.f;
  for (int I = 0; I < Nf; ++I) {
    const float4* qr = (const float4*)&Qs[I * 32];
    float s = 0.f;
#pragma unroll
    for (int m4 = 0; m4 < 8; ++m4) {
      float4 qv = qr[m4];
      s += kreg[m4 * 4 + 0] * qv.x + kreg[m4 * 4 + 1] * qv.y +
           kreg[m4 * 4 + 2] * qv.z + kreg[m4 * 4 + 3] * qv.w;
    }
    float wgt = __expf(s) * inv[I];
    const float4* vr = (const float4*)&Vs[I * 32];
#pragma unroll
    for (int m4 = 0; m4 < 8; ++m4) {
      float4 vv = vr[m4];
      o[m4 * 4 + 0] += wgt * vv.x;
      o[m4 * 4 + 1] += wgt * vv.y;
      o[m4 * 4 + 2] += wgt * vv.z;
      o[m4 * 4 + 3] += wgt * vv.w;
    }
  }
  // temporal[h,m,i,j] -> At[(i*P + j0+jj)*512 + h*32 + m]  (next GEMM's A layout)
  float* ob = At + ((size_t)(t * Pp + j0 + jj) * OUTC + h * Mm);
#pragma unroll
  for (int m4 = 0; m4 < 8; ++m4) *(float4*)&ob[m4 * 4] = *(const float4*)&o[m4 * 4];
}

// ---------------------------------------------------------------------------
// Point attention (standard): one block per (h, ii in chunk); thread j = query.
// P is the (w,h,ii,j,m) chunk; PA is the destination rows (chunk base).
__global__ __launch_bounds__(256) void point_attn(const float* __restrict__ P,
                                                  float* __restrict__ PA,
                                                  int icShift) {
  const int IC = 1 << icShift;
  const int h  = blockIdx.x >> icShift;
  const int ii = blockIdx.x & (IC - 1);
  const int t  = threadIdx.x;
  __shared__ __align__(16) float Ks[Pp * Mm];
  __shared__ __align__(16) float Vs[Pp * Mm];
  const size_t WC = (size_t)(Hh << icShift) * (Pp * Mm);
  const float* qb = P + (size_t)(h * IC + ii) * (Pp * Mm);
  const float* kb = qb + WC;
  const float* vb = qb + 2 * WC;
#pragma unroll
  for (int u = 0; u < 8; ++u) {
    int idx = t + u * 256;
    ((float4*)Ks)[idx] = ((const float4*)kb)[idx];
    ((float4*)Vs)[idx] = ((const float4*)vb)[idx];
  }
  __syncthreads();

  float q[32];
#pragma unroll
  for (int m4 = 0; m4 < 8; ++m4) *(float4*)&q[m4 * 4] = *(const float4*)&qb[t * 32 + m4 * 4];
  float o[32];
#pragma unroll
  for (int m = 0; m < 32; ++m) o[m] = 0.f;
  float sum = 0.f;
  for (int J = 0; J < Pp; ++J) {
    const float4* kr = (const float4*)&Ks[J * 32];
    float s = 0.f;
#pragma unroll
    for (int m4 = 0; m4 < 8; ++m4) {
      float4 kv = kr[m4];
      s += q[m4 * 4 + 0] * kv.x + q[m4 * 4 + 1] * kv.y +
           q[m4 * 4 + 2] * kv.z + q[m4 * 4 + 3] * kv.w;
    }
    float e = __expf(s);   // scores O(0.1); no max-subtraction needed
    sum += e;
    const float4* vr = (const float4*)&Vs[J * 32];
#pragma unroll
    for (int m4 = 0; m4 < 8; ++m4) {
      float4 vv = vr[m4];
      o[m4 * 4 + 0] += e * vv.x;
      o[m4 * 4 + 1] += e * vv.y;
      o[m4 * 4 + 2] += e * vv.z;
      o[m4 * 4 + 3] += e * vv.w;
    }
  }
  float rinv = 1.f / sum;
  // pa[i,j,h,m] -> PA[(ii*P + j)*512 + h*32 + m]  (in-place over consumed At rows)
  float* ob = PA + ((size_t)(ii * Pp + t) * OUTC + h * Mm);
#pragma unroll
  for (int m4 = 0; m4 < 8; ++m4) {
    float4 v;
    v.x = o[m4 * 4 + 0] * rinv;
    v.y = o[m4 * 4 + 1] * rinv;
    v.z = o[m4 * 4 + 2] * rinv;
    v.w = o[m4 * 4 + 3] * rinv;
    *(float4*)&ob[m4 * 4] = v;
  }
}

// ---------------------------------------------------------------------------
extern "C" void kernel_launch(void* const* d_in, const int* in_sizes, int n_in,
                              void* d_out, int out_size, void* d_ws, size_t ws_size,
                              hipStream_t stream) {
  const float* x  = (const float*)d_in[0];
  const float* Wt = (const float*)d_in[1];
  const float* Wp = (const float*)d_in[2];
  const float* W1 = (const float*)d_in[3];
  const float* b1 = (const float*)d_in[4];
  const float* W2 = (const float*)d_in[5];
  const float* b2 = (const float*)d_in[6];
  float* out = (float*)d_out;
  float* ws  = (float*)d_ws;

  // d_out (32768x512 fp32) doubles as the activation matrix At/PA: every stage
  // that reads a row range finishes (stream-ordered) before the next kernel
  // overwrites that range. Workspace holds only a chunk buffer + repacked B's.
  float* At = out;

  // Adaptive chunk sizes so ws usage always fits ws_size (tiers: 72/38/22/13 MB).
  const size_t bF = 393216 + 786432;
  size_t availF = ws_size / 4;
  size_t chF; int RM, IC, JC;
  if      (availF >= 16777216 + bF) { chF = 16777216; RM = 8192; IC = 32; JC = 64; }
  else if (availF >=  8388608 + bF) { chF =  8388608; RM = 4096; IC = 16; JC = 32; }
  else if (availF >=  4194304 + bF) { chF =  4194304; RM = 2048; IC =  8; JC = 16; }
  else                              { chF =  2097152; RM = 1024; IC =  4; JC =  8; }
  float* CH = ws;
  float* B1 = ws + chF;
  float* B2 = B1 + 393216;
  const int jcS = __builtin_ctz((unsigned)JC);
  const int icS = __builtin_ctz((unsigned)IC);

  repack_b1<<<1536, 256, 0, stream>>>(Wt, B1);
  repack_b2<<<3072, 256, 0, stream>>>(Wp, B2);

  // 1) temporal QKV + attention, streamed over j-chunks of JC points.
  for (int j0 = 0; j0 < Pp; j0 += JC) {
    gemm128<256, 1536, 1, 1><<<dim3(12, JC), 256, 0, stream>>>(x, B1, CH, nullptr, j0, jcS, JC);
    temporal_attn<<<Hh * JC, 128, 0, stream>>>(CH, At, j0, jcS);
  }

  // 2) point QKV + attention, streamed over i-chunks of IC frames (in-place rows).
  for (int i0 = 0; i0 < Nf; i0 += IC) {
    float* Arows = At + (size_t)i0 * Pp * OUTC;
    gemm128<512, 1536, 0, 2><<<dim3(12, IC * 2), 256, 0, stream>>>(Arows, B2, CH, nullptr, 0, 0, IC);
    point_attn<<<Hh * IC, 256, 0, stream>>>(CH, Arows, icS);
  }

  // 3) MLP streamed over row-chunks of RM (hidden chunk reuses CH; writes rows
  //    of d_out that gemm1 of the same chunk has already consumed).
  for (int r0 = 0; r0 < Nf * Pp; r0 += RM) {
    gemm128<512, 2048, 0, 0><<<dim3(16, RM / 128), 256, 0, stream>>>(At + (size_t)r0 * OUTC, W1, CH, b1, 0, 0, 0);
    gemm128<2048, 512, 0, 0><<<dim3(4, RM / 128), 256, 0, stream>>>(CH, W2, out + (size_t)r0 * OUTC, b2, 0, 0, 0);
  }
}

// Round 3
// 1389.337 us; speedup vs baseline: 2.7669x; 2.7669x over previous
//
#include <hip/hip_runtime.h>
#include <cstddef>
#include <cstdint>

constexpr int Nf = 128, Pp = 256, Dd = 256, Hh = 16, Mm = 32;
constexpr int OUTC = 512, HID = 2048, C3 = 1536;

typedef short short8 __attribute__((ext_vector_type(8)));   // 8 bf16 (4 VGPRs)
typedef float f32x4 __attribute__((ext_vector_type(4)));    // 4 fp32 acc

// fp32 -> bf16 round-to-nearest-even
__device__ inline unsigned short f2bf(float f) {
  unsigned u = __float_as_uint(f);
  u += 0x7fffu + ((u >> 16) & 1u);
  return (unsigned short)(u >> 16);
}
__device__ inline unsigned pk2(float a, float b) {
  return (unsigned)f2bf(a) | ((unsigned)f2bf(b) << 16);
}
__device__ inline float bflo(unsigned u) { return __uint_as_float(u << 16); }
__device__ inline float bfhi(unsigned u) { return __uint_as_float(u & 0xffff0000u); }
__device__ inline void up8(uint4 v, float* d) {
  d[0] = bflo(v.x); d[1] = bfhi(v.x); d[2] = bflo(v.y); d[3] = bfhi(v.y);
  d[4] = bflo(v.z); d[5] = bfhi(v.z); d[6] = bflo(v.w); d[7] = bfhi(v.w);
}

// ---------------------------------------------------------------------------
// Conversion / repack kernels (all outputs bf16; B matrices transposed k-contig)
__global__ __launch_bounds__(256) void conv_x(const float* __restrict__ x,
                                              short* __restrict__ xb) {
  int idx = blockIdx.x * 256 + threadIdx.x;  // 8 elems each, 8,388,608 total
  const float4* s = (const float4*)x + (size_t)idx * 2;
  float4 a = s[0], c = s[1];
  uint4 o;
  o.x = pk2(a.x, a.y); o.y = pk2(a.z, a.w);
  o.z = pk2(c.x, c.y); o.w = pk2(c.z, c.w);
  ((uint4*)xb)[idx] = o;
}

// B1t[c][d], c = w*512+h*32+m (1536 x 256)
__global__ void repack_b1t(const float* __restrict__ Wt, short* __restrict__ B1t) {
  int idx = blockIdx.x * 256 + threadIdx.x;  // 393216
  int c = idx >> 8, d = idx & 255;
  int w = c >> 9, h = (c >> 5) & 15, m = c & 31;
  B1t[idx] = (short)f2bf(Wt[((w * Dd + d) * Hh + h) * Mm + m]);
}
// B2t[c][k], k = HH*32+MM (1536 x 512)
__global__ void repack_b2t(const float* __restrict__ Wp, short* __restrict__ B2t) {
  int idx = blockIdx.x * 256 + threadIdx.x;  // 786432
  int c = idx >> 9, k = idx & 511;
  int w = c >> 9, h = (c >> 5) & 15, m = c & 31;
  int HH = k >> 5, MM = k & 31;
  B2t[idx] = (short)f2bf(Wp[(((w * Hh + h) * Mm + m) * Hh + HH) * Mm + MM]);
}
// W1t[n][k] (2048 x 512); W1 is (512, 2048) row-major
__global__ void repack_w1t(const float* __restrict__ W1, short* __restrict__ W1t) {
  int idx = blockIdx.x * 256 + threadIdx.x;  // 1048576
  int n = idx >> 9, k = idx & 511;
  W1t[idx] = (short)f2bf(W1[(size_t)k * HID + n]);
}
// W2t[n][k] (512 x 2048); W2 is (2048, 512) row-major
__global__ void repack_w2t(const float* __restrict__ W2, short* __restrict__ W2t) {
  int idx = blockIdx.x * 256 + threadIdx.x;  // 1048576
  int n = idx >> 11, k = idx & 2047;
  W2t[idx] = (short)f2bf(W2[(size_t)k * OUTC + n]);
}

// ---------------------------------------------------------------------------
// bf16 MFMA GEMM, m97 structure: 128x128 tile, BK=32, 256 thr = 4 waves,
// each wave a 64x64 quadrant via 4x4 of 16x16x32 MFMA. A row-major k-contig,
// Bt = B^T (n-major, k-contig). Staging via global_load_lds width=16.
// AMAP=1: row rr=(i<<pshift)+jj -> A row (i<<8)+j0+jj (temporal chunking of x).
// EPI=0: C[row][col] + bias (OUTT 0=bf16, 1=fp32).
// EPI=1: scatter bf16 to (w,h,jj,i,m), pc=JC. EPI=2: scatter to (w,h,ii,j,m), pc=IC.
template <int KDIM, int NCOLS, int AMAP, int EPI, int OUTT>
__global__ __launch_bounds__(256) void gemm_mfma(const short* __restrict__ A,
                                                 const short* __restrict__ Bt,
                                                 void* __restrict__ Cv,
                                                 const float* __restrict__ bias,
                                                 int j0, int pshift, int pc) {
  __shared__ short As[128 * 32];   // [r][k] 8 KB
  __shared__ short Bs[128 * 32];   // [n][k] 8 KB
  const int t = threadIdx.x;
  const int wv = t >> 6, ln = t & 63;
  const int wr = wv >> 1, wc = wv & 1;
  const int lr = ln & 15, kq = ln >> 4;
  const int row0 = blockIdx.y * 128, col0 = blockIdx.x * 128;

  f32x4 acc[4][4];
#pragma unroll
  for (int i = 0; i < 4; ++i)
#pragma unroll
    for (int j = 0; j < 4; ++j) acc[i][j] = {0.f, 0.f, 0.f, 0.f};

  for (int kt = 0; kt < KDIM; kt += 32) {
#pragma unroll
    for (int u = 0; u < 2; ++u) {    // A tile: 512 16B segs, 2 per thread
      int seg = wv * 128 + u * 64 + ln;
      int r = seg >> 2, kg = seg & 3;
      int rr = row0 + r;
      size_t arow;
      if (AMAP == 0) arow = (size_t)rr;
      else { int i = rr >> pshift, jj = rr & (pc - 1); arow = (size_t)((i << 8) + j0 + jj); }
      const short* gp = A + arow * KDIM + kt + kg * 8;
      __builtin_amdgcn_global_load_lds(
          (const __attribute__((address_space(1))) void*)gp,
          (__attribute__((address_space(3))) void*)&As[(wv * 128 + u * 64) * 8],
          16, 0, 0);
    }
#pragma unroll
    for (int u = 0; u < 2; ++u) {    // B tile
      int seg = wv * 128 + u * 64 + ln;
      int r = seg >> 2, kg = seg & 3;
      const short* gp = Bt + (size_t)(col0 + r) * KDIM + kt + kg * 8;
      __builtin_amdgcn_global_load_lds(
          (const __attribute__((address_space(1))) void*)gp,
          (__attribute__((address_space(3))) void*)&Bs[(wv * 128 + u * 64) * 8],
          16, 0, 0);
    }
    __syncthreads();
    short8 a[4], b[4];
#pragma unroll
    for (int ti = 0; ti < 4; ++ti)
      a[ti] = *(const short8*)&As[(wr * 64 + ti * 16 + lr) * 32 + kq * 8];
#pragma unroll
    for (int tj = 0; tj < 4; ++tj)
      b[tj] = *(const short8*)&Bs[(wc * 64 + tj * 16 + lr) * 32 + kq * 8];
#pragma unroll
    for (int ti = 0; ti < 4; ++ti)
#pragma unroll
      for (int tj = 0; tj < 4; ++tj)
        acc[ti][tj] = __builtin_amdgcn_mfma_f32_16x16x32_bf16(a[ti], b[tj], acc[ti][tj], 0, 0, 0);
    __syncthreads();
  }

  // epilogue: C/D layout col=lane&15, row=(lane>>4)*4+reg  [m89/m91-verified]
#pragma unroll
  for (int tj = 0; tj < 4; ++tj) {
    int gcol = col0 + wc * 64 + tj * 16 + lr;
    float bv = (EPI == 0) ? bias[gcol] : 0.f;
#pragma unroll
    for (int ti = 0; ti < 4; ++ti) {
#pragma unroll
      for (int rg = 0; rg < 4; ++rg) {
        int grow = row0 + wr * 64 + ti * 16 + kq * 4 + rg;
        float val = acc[ti][tj][rg];
        if (EPI == 0) {
          val += bv;
          if (OUTT == 0) ((short*)Cv)[(size_t)grow * NCOLS + gcol] = (short)f2bf(val);
          else           ((float*)Cv)[(size_t)grow * NCOLS + gcol] = val;
        } else {
          int w = gcol >> 9, h = (gcol >> 5) & 15, m = gcol & 31;
          size_t addr;
          if (EPI == 1) {
            int i = grow >> pshift, jj = grow & (pc - 1);
            addr = (((size_t)(w * Hh + h) * pc + jj) * Nf + i) * Mm + m;
          } else {
            int ii = grow >> 8, j = grow & 255;
            addr = (((size_t)(w * Hh + h) * pc + ii) * Pp + j) * Mm + m;
          }
          ((short*)Cv)[addr] = (short)f2bf(val);
        }
      }
    }
  }
}

// ---------------------------------------------------------------------------
// Temporal attention (transposed form per reference einsum), fp32 math,
// bf16 I/O. One block per (h, jj); 128 threads. T = (w,h,jj,i,m) bf16 chunk.
__global__ __launch_bounds__(128) void temporal_attn(const short* __restrict__ T,
                                                     short* __restrict__ At,
                                                     int j0, int jcShift) {
  const int JC = 1 << jcShift;
  const int h  = blockIdx.x >> jcShift;
  const int jj = blockIdx.x & (JC - 1);
  const int t  = threadIdx.x;
  __shared__ __align__(16) float Qs[Nf * Mm];
  __shared__ __align__(16) float Ks[Nf * Mm];
  __shared__ __align__(16) float Vs[Nf * Mm];
  __shared__ float inv[Nf];
  const size_t WC = (size_t)(Hh << jcShift) * (Nf * Mm);
  const short* qb = T + (size_t)(h * JC + jj) * (Nf * Mm);
  const short* kb = qb + WC;
  const short* vb = qb + 2 * WC;
#pragma unroll
  for (int u = 0; u < 4; ++u) {
    int idx = t + u * 128;   // uint4 = 8 bf16
    up8(((const uint4*)qb)[idx], &Qs[idx * 8]);
    up8(((const uint4*)kb)[idx], &Ks[idx * 8]);
    up8(((const uint4*)vb)[idx], &Vs[idx * 8]);
  }
  __syncthreads();

  float q[32];
#pragma unroll
  for (int m4 = 0; m4 < 8; ++m4) *(float4*)&q[m4 * 4] = *(const float4*)&Qs[t * 32 + m4 * 4];
  float ssum = 0.f;
  for (int b = 0; b < Nf; ++b) {
    const float4* kr = (const float4*)&Ks[b * 32];
    float s = 0.f;
#pragma unroll
    for (int m4 = 0; m4 < 8; ++m4) {
      float4 kv = kr[m4];
      s += q[m4 * 4 + 0] * kv.x + q[m4 * 4 + 1] * kv.y +
           q[m4 * 4 + 2] * kv.z + q[m4 * 4 + 3] * kv.w;
    }
    ssum += __expf(s);
  }
  inv[t] = 1.f / ssum;
  __syncthreads();

  float kreg[32];
#pragma unroll
  for (int m4 = 0; m4 < 8; ++m4) *(float4*)&kreg[m4 * 4] = *(const float4*)&Ks[t * 32 + m4 * 4];
  float o[32];
#pragma unroll
  for (int m = 0; m < 32; ++m) o[m] = 0.f;
  for (int I = 0; I < Nf; ++I) {
    const float4* qr = (const float4*)&Qs[I * 32];
    float s = 0.f;
#pragma unroll
    for (int m4 = 0; m4 < 8; ++m4) {
      float4 qv = qr[m4];
      s += kreg[m4 * 4 + 0] * qv.x + kreg[m4 * 4 + 1] * qv.y +
           kreg[m4 * 4 + 2] * qv.z + kreg[m4 * 4 + 3] * qv.w;
    }
    float wgt = __expf(s) * inv[I];
    const float4* vr = (const float4*)&Vs[I * 32];
#pragma unroll
    for (int m4 = 0; m4 < 8; ++m4) {
      float4 vv = vr[m4];
      o[m4 * 4 + 0] += wgt * vv.x;
      o[m4 * 4 + 1] += wgt * vv.y;
      o[m4 * 4 + 2] += wgt * vv.z;
      o[m4 * 4 + 3] += wgt * vv.w;
    }
  }
  short* ob = At + ((size_t)(t * Pp + j0 + jj) * OUTC + h * Mm);
#pragma unroll
  for (int m4 = 0; m4 < 4; ++m4) {
    uint4 v;
    v.x = pk2(o[m4 * 8 + 0], o[m4 * 8 + 1]);
    v.y = pk2(o[m4 * 8 + 2], o[m4 * 8 + 3]);
    v.z = pk2(o[m4 * 8 + 4], o[m4 * 8 + 5]);
    v.w = pk2(o[m4 * 8 + 6], o[m4 * 8 + 7]);
    ((uint4*)ob)[m4] = v;
  }
}

// ---------------------------------------------------------------------------
// Point attention (standard), fp32 math, bf16 I/O. One block per (h, ii);
// thread j = query. P = (w,h,ii,j,m) bf16 chunk; PA = At rows (bf16).
__global__ __launch_bounds__(256) void point_attn(const short* __restrict__ P,
                                                  short* __restrict__ PA,
                                                  int icShift) {
  const int IC = 1 << icShift;
  const int h  = blockIdx.x >> icShift;
  const int ii = blockIdx.x & (IC - 1);
  const int t  = threadIdx.x;
  __shared__ __align__(16) float Ks[Pp * Mm];
  __shared__ __align__(16) float Vs[Pp * Mm];
  const size_t WC = (size_t)(Hh << icShift) * (Pp * Mm);
  const short* qb = P + (size_t)(h * IC + ii) * (Pp * Mm);
  const short* kb = qb + WC;
  const short* vb = qb + 2 * WC;
#pragma unroll
  for (int u = 0; u < 4; ++u) {
    int idx = t + u * 256;
    up8(((const uint4*)kb)[idx], &Ks[idx * 8]);
    up8(((const uint4*)vb)[idx], &Vs[idx * 8]);
  }
  __syncthreads();

  float q[32];
#pragma unroll
  for (int m4 = 0; m4 < 4; ++m4) up8(((const uint4*)(qb + t * 32))[m4], &q[m4 * 8]);
  float o[32];
#pragma unroll
  for (int m = 0; m < 32; ++m) o[m] = 0.f;
  float sum = 0.f;
  for (int J = 0; J < Pp; ++J) {
    const float4* kr = (const float4*)&Ks[J * 32];
    float s = 0.f;
#pragma unroll
    for (int m4 = 0; m4 < 8; ++m4) {
      float4 kv = kr[m4];
      s += q[m4 * 4 + 0] * kv.x + q[m4 * 4 + 1] * kv.y +
           q[m4 * 4 + 2] * kv.z + q[m4 * 4 + 3] * kv.w;
    }
    float e = __expf(s);
    sum += e;
    const float4* vr = (const float4*)&Vs[J * 32];
#pragma unroll
    for (int m4 = 0; m4 < 8; ++m4) {
      float4 vv = vr[m4];
      o[m4 * 4 + 0] += e * vv.x;
      o[m4 * 4 + 1] += e * vv.y;
      o[m4 * 4 + 2] += e * vv.z;
      o[m4 * 4 + 3] += e * vv.w;
    }
  }
  float rinv = 1.f / sum;
  short* ob = PA + ((size_t)(ii * Pp + t) * OUTC + h * Mm);
#pragma unroll
  for (int m4 = 0; m4 < 4; ++m4) {
    uint4 v;
    v.x = pk2(o[m4 * 8 + 0] * rinv, o[m4 * 8 + 1] * rinv);
    v.y = pk2(o[m4 * 8 + 2] * rinv, o[m4 * 8 + 3] * rinv);
    v.z = pk2(o[m4 * 8 + 4] * rinv, o[m4 * 8 + 5] * rinv);
    v.w = pk2(o[m4 * 8 + 6] * rinv, o[m4 * 8 + 7] * rinv);
    ((uint4*)ob)[m4] = v;
  }
}

// ---------------------------------------------------------------------------
extern "C" void kernel_launch(void* const* d_in, const int* in_sizes, int n_in,
                              void* d_out, int out_size, void* d_ws, size_t ws_size,
                              hipStream_t stream) {
  const float* x  = (const float*)d_in[0];
  const float* Wt = (const float*)d_in[1];
  const float* Wp = (const float*)d_in[2];
  const float* W1 = (const float*)d_in[3];
  const float* b1 = (const float*)d_in[4];
  const float* W2 = (const float*)d_in[5];
  const float* b2 = (const float*)d_in[6];
  float* out = (float*)d_out;
  short* ws  = (short*)d_ws;

  // bf16-element budget; fixed part = xbf(8.39M) + At(16.78M) + weights(3.28M)
  const size_t fixedH = 8388608 + 16777216 + 393216 + 786432 + 1048576 + 1048576;
  size_t availH = ws_size / 2;
  size_t chF; int RM, JC, IC;
  if      (availH >= fixedH + 67108864) { chF = 67108864; RM = 32768; JC = 64; IC = 32; }
  else if (availH >= fixedH + 16777216) { chF = 16777216; RM = 8192;  JC = 64; IC = 32; }
  else if (availH >= fixedH + 8388608)  { chF = 8388608;  RM = 4096;  JC = 32; IC = 16; }
  else                                  { chF = 4194304;  RM = 2048;  JC = 16; IC = 8;  }
  short* CH  = ws;               // QKV chunks / MLP hidden (bf16)
  short* xbf = CH + chF;
  short* At  = xbf + 8388608;    // temporal out -> point-attn out (bf16, in-place)
  short* B1t = At + 16777216;
  short* B2t = B1t + 393216;
  short* W1t = B2t + 786432;
  short* W2t = W1t + 1048576;
  const int jcS = __builtin_ctz((unsigned)JC);
  const int icS = __builtin_ctz((unsigned)IC);

  conv_x<<<4096, 256, 0, stream>>>(x, xbf);
  repack_b1t<<<1536, 256, 0, stream>>>(Wt, B1t);
  repack_b2t<<<3072, 256, 0, stream>>>(Wp, B2t);
  repack_w1t<<<4096, 256, 0, stream>>>(W1, W1t);
  repack_w2t<<<4096, 256, 0, stream>>>(W2, W2t);

  // 1) temporal QKV + attention, streamed over j-chunks
  for (int j0 = 0; j0 < Pp; j0 += JC) {
    gemm_mfma<256, 1536, 1, 1, 0><<<dim3(12, JC), 256, 0, stream>>>(xbf, B1t, CH, nullptr, j0, jcS, JC);
    temporal_attn<<<Hh * JC, 128, 0, stream>>>(CH, At, j0, jcS);
  }
  // 2) point QKV + attention, streamed over i-chunks (in-place rows of At)
  for (int i0 = 0; i0 < Nf; i0 += IC) {
    short* Arows = At + (size_t)i0 * Pp * OUTC;
    gemm_mfma<512, 1536, 0, 2, 0><<<dim3(12, IC * 2), 256, 0, stream>>>(Arows, B2t, CH, nullptr, 0, 0, IC);
    point_attn<<<Hh * IC, 256, 0, stream>>>(CH, Arows, icS);
  }
  // 3) MLP: At @ W1 + b1 -> hidden (bf16, CH); hidden @ W2 + b2 -> out (fp32)
  for (int r0 = 0; r0 < Nf * Pp; r0 += RM) {
    gemm_mfma<512, 2048, 0, 0, 0><<<dim3(16, RM / 128), 256, 0, stream>>>(At + (size_t)r0 * OUTC, W1t, CH, b1, 0, 0, 0);
    gemm_mfma<2048, 512, 0, 0, 1><<<dim3(4, RM / 128), 256, 0, stream>>>(CH, W2t, out + (size_t)r0 * OUTC, b2, 0, 0, 0);
  }
}

// Round 4
// 610.827 us; speedup vs baseline: 6.2933x; 2.2745x over previous
//
#include <hip/hip_runtime.h>
#include <cstddef>
#include <cstdint>

constexpr int Nf = 128, Pp = 256, Dd = 256, Hh = 16, Mm = 32;
constexpr int OUTC = 512, HID = 2048, C3 = 1536;

typedef short short8 __attribute__((ext_vector_type(8)));   // 8 bf16 (4 VGPRs)
typedef float f32x4 __attribute__((ext_vector_type(4)));    // 4 fp32 acc

// fp32 -> bf16 round-to-nearest-even
__device__ inline unsigned short f2bf(float f) {
  unsigned u = __float_as_uint(f);
  u += 0x7fffu + ((u >> 16) & 1u);
  return (unsigned short)(u >> 16);
}
__device__ inline unsigned pk2(float a, float b) {
  return (unsigned)f2bf(a) | ((unsigned)f2bf(b) << 16);
}

// ---------------------------------------------------------------------------
// Conversion / repack kernels (all outputs bf16; B matrices transposed k-contig)
__global__ __launch_bounds__(256) void conv_x(const float* __restrict__ x,
                                              short* __restrict__ xb) {
  int idx = blockIdx.x * 256 + threadIdx.x;
  const float4* s = (const float4*)x + (size_t)idx * 2;
  float4 a = s[0], c = s[1];
  uint4 o;
  o.x = pk2(a.x, a.y); o.y = pk2(a.z, a.w);
  o.z = pk2(c.x, c.y); o.w = pk2(c.z, c.w);
  ((uint4*)xb)[idx] = o;
}

__global__ void repack_b1t(const float* __restrict__ Wt, short* __restrict__ B1t) {
  int idx = blockIdx.x * 256 + threadIdx.x;  // 393216
  int c = idx >> 8, d = idx & 255;
  int w = c >> 9, h = (c >> 5) & 15, m = c & 31;
  B1t[idx] = (short)f2bf(Wt[((w * Dd + d) * Hh + h) * Mm + m]);
}
__global__ void repack_b2t(const float* __restrict__ Wp, short* __restrict__ B2t) {
  int idx = blockIdx.x * 256 + threadIdx.x;  // 786432
  int c = idx >> 9, k = idx & 511;
  int w = c >> 9, h = (c >> 5) & 15, m = c & 31;
  int HH = k >> 5, MM = k & 31;
  B2t[idx] = (short)f2bf(Wp[(((w * Hh + h) * Mm + m) * Hh + HH) * Mm + MM]);
}
__global__ void repack_w1t(const float* __restrict__ W1, short* __restrict__ W1t) {
  int idx = blockIdx.x * 256 + threadIdx.x;  // 1048576
  int n = idx >> 9, k = idx & 511;
  W1t[idx] = (short)f2bf(W1[(size_t)k * HID + n]);
}
__global__ void repack_w2t(const float* __restrict__ W2, short* __restrict__ W2t) {
  int idx = blockIdx.x * 256 + threadIdx.x;  // 1048576
  int n = idx >> 11, k = idx & 2047;
  W2t[idx] = (short)f2bf(W2[(size_t)k * OUTC + n]);
}

// ---------------------------------------------------------------------------
// bf16 MFMA GEMM (m97 structure) — unchanged from round 3 (verified).
template <int KDIM, int NCOLS, int AMAP, int EPI, int OUTT>
__global__ __launch_bounds__(256) void gemm_mfma(const short* __restrict__ A,
                                                 const short* __restrict__ Bt,
                                                 void* __restrict__ Cv,
                                                 const float* __restrict__ bias,
                                                 int j0, int pshift, int pc) {
  __shared__ short As[128 * 32];
  __shared__ short Bs[128 * 32];
  const int t = threadIdx.x;
  const int wv = t >> 6, ln = t & 63;
  const int wr = wv >> 1, wc = wv & 1;
  const int lr = ln & 15, kq = ln >> 4;
  const int row0 = blockIdx.y * 128, col0 = blockIdx.x * 128;

  f32x4 acc[4][4];
#pragma unroll
  for (int i = 0; i < 4; ++i)
#pragma unroll
    for (int j = 0; j < 4; ++j) acc[i][j] = {0.f, 0.f, 0.f, 0.f};

  for (int kt = 0; kt < KDIM; kt += 32) {
#pragma unroll
    for (int u = 0; u < 2; ++u) {
      int seg = wv * 128 + u * 64 + ln;
      int r = seg >> 2, kg = seg & 3;
      int rr = row0 + r;
      size_t arow;
      if (AMAP == 0) arow = (size_t)rr;
      else { int i = rr >> pshift, jj = rr & (pc - 1); arow = (size_t)((i << 8) + j0 + jj); }
      const short* gp = A + arow * KDIM + kt + kg * 8;
      __builtin_amdgcn_global_load_lds(
          (const __attribute__((address_space(1))) void*)gp,
          (__attribute__((address_space(3))) void*)&As[(wv * 128 + u * 64) * 8], 16, 0, 0);
    }
#pragma unroll
    for (int u = 0; u < 2; ++u) {
      int seg = wv * 128 + u * 64 + ln;
      int r = seg >> 2, kg = seg & 3;
      const short* gp = Bt + (size_t)(col0 + r) * KDIM + kt + kg * 8;
      __builtin_amdgcn_global_load_lds(
          (const __attribute__((address_space(1))) void*)gp,
          (__attribute__((address_space(3))) void*)&Bs[(wv * 128 + u * 64) * 8], 16, 0, 0);
    }
    __syncthreads();
    short8 a[4], b[4];
#pragma unroll
    for (int ti = 0; ti < 4; ++ti)
      a[ti] = *(const short8*)&As[(wr * 64 + ti * 16 + lr) * 32 + kq * 8];
#pragma unroll
    for (int tj = 0; tj < 4; ++tj)
      b[tj] = *(const short8*)&Bs[(wc * 64 + tj * 16 + lr) * 32 + kq * 8];
#pragma unroll
    for (int ti = 0; ti < 4; ++ti)
#pragma unroll
      for (int tj = 0; tj < 4; ++tj)
        acc[ti][tj] = __builtin_amdgcn_mfma_f32_16x16x32_bf16(a[ti], b[tj], acc[ti][tj], 0, 0, 0);
    __syncthreads();
  }

#pragma unroll
  for (int tj = 0; tj < 4; ++tj) {
    int gcol = col0 + wc * 64 + tj * 16 + lr;
    float bv = (EPI == 0) ? bias[gcol] : 0.f;
#pragma unroll
    for (int ti = 0; ti < 4; ++ti) {
#pragma unroll
      for (int rg = 0; rg < 4; ++rg) {
        int grow = row0 + wr * 64 + ti * 16 + kq * 4 + rg;
        float val = acc[ti][tj][rg];
        if (EPI == 0) {
          val += bv;
          if (OUTT == 0) ((short*)Cv)[(size_t)grow * NCOLS + gcol] = (short)f2bf(val);
          else           ((float*)Cv)[(size_t)grow * NCOLS + gcol] = val;
        } else {
          int w = gcol >> 9, h = (gcol >> 5) & 15, m = gcol & 31;
          size_t addr;
          if (EPI == 1) {
            int i = grow >> pshift, jj = grow & (pc - 1);
            addr = (((size_t)(w * Hh + h) * pc + jj) * Nf + i) * Mm + m;
          } else {
            int ii = grow >> 8, j = grow & 255;
            addr = (((size_t)(w * Hh + h) * pc + ii) * Pp + j) * Mm + m;
          }
          ((short*)Cv)[addr] = (short)f2bf(val);
        }
      }
    }
  }
}

// ---------------------------------------------------------------------------
// Temporal attention, MFMA version. One block (256 thr, 4 waves) per (h, jj).
// S[I][i] = q_I·k_i via MFMA (rows I, cols i). inv[I] = 1/sum_i exp(S[I][i]).
// out[i][m] = sum_I exp(S[I][i])*inv[I]*V[I][m] via MFMA with A = W^T from LDS.
// LDS (shorts): Qs 0..4096, Ks 4096..8192, Vt 8192..12544 (32x136),
//               Wt 12544..29952 (128x136), rs(fp32) 29952..30464. 60928 B.
__global__ __launch_bounds__(256) void temporal_attn_mfma(const short* __restrict__ T,
                                                          short* __restrict__ At,
                                                          int j0, int jcShift) {
  constexpr int QsO = 0, KsO = 4096, VtO = 8192, WtO = 12544, RsO = 29952;
  __shared__ __align__(16) short lds[30464];
  float* rs = (float*)&lds[RsO];
  const int JC = 1 << jcShift;
  const int h  = blockIdx.x >> jcShift;
  const int jj = blockIdx.x & (JC - 1);
  const int t  = threadIdx.x;
  const int wv = t >> 6, ln = t & 63;
  const int wr = wv >> 1, wc = wv & 1;
  const int lr = ln & 15, kq = ln >> 4;
  const size_t WC = (size_t)(Hh << jcShift) * 4096;
  const short* qb = T + (size_t)(h * JC + jj) * 4096;
  const short* kb = qb + WC;
  const short* vb = qb + 2 * WC;

#pragma unroll
  for (int u = 0; u < 2; ++u) {   // stage Q,K (8 KB each)
    int seg = wv * 2 + u;
    __builtin_amdgcn_global_load_lds(
        (const __attribute__((address_space(1))) void*)(qb + seg * 512 + ln * 8),
        (__attribute__((address_space(3))) void*)&lds[QsO + seg * 512], 16, 0, 0);
    __builtin_amdgcn_global_load_lds(
        (const __attribute__((address_space(1))) void*)(kb + seg * 512 + ln * 8),
        (__attribute__((address_space(3))) void*)&lds[KsO + seg * 512], 16, 0, 0);
  }
#pragma unroll
  for (int u = 0; u < 2; ++u) {   // stage V transposed: Vt[m][I], stride 136
    int idx = t + u * 256;
    int I = idx >> 2, m0 = (idx & 3) * 8;
    uint4 v = *(const uint4*)(vb + idx * 8);
    const short* vs = (const short*)&v;
#pragma unroll
    for (int q = 0; q < 8; ++q) lds[VtO + (m0 + q) * 136 + I] = vs[q];
  }
  __syncthreads();

  // S-MFMA: wave quadrant rows wr*64 (I), cols wc*64 (i)
  short8 af[4], bf[4];
#pragma unroll
  for (int ti = 0; ti < 4; ++ti)
    af[ti] = *(const short8*)&lds[QsO + (wr * 64 + ti * 16 + lr) * 32 + kq * 8];
#pragma unroll
  for (int tj = 0; tj < 4; ++tj)
    bf[tj] = *(const short8*)&lds[KsO + (wc * 64 + tj * 16 + lr) * 32 + kq * 8];
  f32x4 e[4][4];
#pragma unroll
  for (int ti = 0; ti < 4; ++ti)
#pragma unroll
    for (int tj = 0; tj < 4; ++tj) e[ti][tj] = {0.f, 0.f, 0.f, 0.f};
#pragma unroll
  for (int ti = 0; ti < 4; ++ti)
#pragma unroll
    for (int tj = 0; tj < 4; ++tj)
      e[ti][tj] = __builtin_amdgcn_mfma_f32_16x16x32_bf16(af[ti], bf[tj], e[ti][tj], 0, 0, 0);

  // exp + per-row partial sums over this wave's 64 cols
  float part[4][4];
#pragma unroll
  for (int ti = 0; ti < 4; ++ti)
#pragma unroll
    for (int r = 0; r < 4; ++r) {
      float p = 0.f;
#pragma unroll
      for (int tj = 0; tj < 4; ++tj) {
        float ex = __expf(e[ti][tj][r]);
        e[ti][tj][r] = ex;
        p += ex;
      }
      part[ti][r] = p;
    }
#pragma unroll
  for (int msk = 1; msk <= 8; msk <<= 1)
#pragma unroll
    for (int ti = 0; ti < 4; ++ti)
#pragma unroll
      for (int r = 0; r < 4; ++r)
        part[ti][r] += __shfl_xor(part[ti][r], msk, 64);
  if (lr == 0) {
#pragma unroll
    for (int ti = 0; ti < 4; ++ti)
#pragma unroll
      for (int r = 0; r < 4; ++r)
        rs[wc * 128 + wr * 64 + ti * 16 + kq * 4 + r] = part[ti][r];
  }
  __syncthreads();

  // scale rows by inv[I], write W^T to LDS: Wt[i][I] (b64 per tile, conflict-free)
#pragma unroll
  for (int ti = 0; ti < 4; ++ti) {
#pragma unroll
    for (int r = 0; r < 4; ++r) {
      int I = wr * 64 + ti * 16 + kq * 4 + r;
      float inv = 1.f / (rs[I] + rs[128 + I]);
#pragma unroll
      for (int tj = 0; tj < 4; ++tj) e[ti][tj][r] *= inv;
    }
#pragma unroll
    for (int tj = 0; tj < 4; ++tj) {
      int i = wc * 64 + tj * 16 + lr;
      int Ib = wr * 64 + ti * 16 + kq * 4;
      uint2 pk;
      pk.x = pk2(e[ti][tj][0], e[ti][tj][1]);
      pk.y = pk2(e[ti][tj][2], e[ti][tj][3]);
      *(uint2*)&lds[WtO + i * 136 + Ib] = pk;
    }
  }
  __syncthreads();

  // O-MFMA: D[i][m] = sum_I Wt[i][I] V[I][m]; wave wv takes rows wv*32..+31
  f32x4 o[2][2];
#pragma unroll
  for (int tr = 0; tr < 2; ++tr)
#pragma unroll
    for (int tm = 0; tm < 2; ++tm) o[tr][tm] = {0.f, 0.f, 0.f, 0.f};
#pragma unroll
  for (int ks = 0; ks < 4; ++ks) {
    short8 ea[2], vf[2];
#pragma unroll
    for (int tr = 0; tr < 2; ++tr)
      ea[tr] = *(const short8*)&lds[WtO + (wv * 32 + tr * 16 + lr) * 136 + ks * 32 + kq * 8];
#pragma unroll
    for (int tm = 0; tm < 2; ++tm)
      vf[tm] = *(const short8*)&lds[VtO + (tm * 16 + lr) * 136 + ks * 32 + kq * 8];
#pragma unroll
    for (int tr = 0; tr < 2; ++tr)
#pragma unroll
      for (int tm = 0; tm < 2; ++tm)
        o[tr][tm] = __builtin_amdgcn_mfma_f32_16x16x32_bf16(ea[tr], vf[tm], o[tr][tm], 0, 0, 0);
  }
  // O -> LDS (alias Qs/Ks region, dead), stride 40 shorts, then coalesced store
#pragma unroll
  for (int tr = 0; tr < 2; ++tr)
#pragma unroll
    for (int tm = 0; tm < 2; ++tm)
#pragma unroll
      for (int r = 0; r < 4; ++r) {
        int row = wv * 32 + tr * 16 + kq * 4 + r;
        lds[row * 40 + tm * 16 + lr] = (short)f2bf(o[tr][tm][r]);
      }
  __syncthreads();
#pragma unroll
  for (int u = 0; u < 2; ++u) {
    int idx = t + u * 256;
    int i = idx >> 2, mg = idx & 3;
    uint4 vv = *(const uint4*)&lds[i * 40 + mg * 8];
    *(uint4*)(At + ((size_t)(i * Pp + j0 + jj) * OUTC + h * 32 + mg * 8)) = vv;
  }
}

// ---------------------------------------------------------------------------
// Point attention, MFMA version. One block per (h, ii, qhalf); 128 queries,
// 256 keys in 2 chunks of 128. S^T[J][j] via MFMA (A=K rows J, B=Q cols j) so
// exp'd scores b64-pack into E[j][J] = A-layout for the PV MFMA. denom[j]
// accumulated across chunks; O normalized in epilogue.
// LDS (shorts): Qs 0..4096, Ks 4096..8192 (per chunk), Vt 8192..12544
//               (32x136, per chunk), E 12544..29952 (128x136), cs/denom
//               (fp32: 2x128 + 128) 29952..30720. 61440 B.
__global__ __launch_bounds__(256) void point_attn_mfma(const short* __restrict__ P,
                                                       short* __restrict__ PA,
                                                       int icShift) {
  constexpr int QsO = 0, KsO = 4096, VtO = 8192, EO = 12544, CsO = 29952;
  __shared__ __align__(16) short lds[30720];
  float* cs    = (float*)&lds[CsO];        // [2][128]
  float* denom = cs + 256;                 // [128]
  const int IC = 1 << icShift;
  const int bx = blockIdx.x;
  const int h    = bx >> (icShift + 1);
  const int rem  = bx & ((IC << 1) - 1);
  const int ii   = rem >> 1;
  const int half = rem & 1;
  const int t  = threadIdx.x;
  const int wv = t >> 6, ln = t & 63;
  const int wr = wv >> 1, wc = wv & 1;
  const int lr = ln & 15, kq = ln >> 4;
  const size_t WC = (size_t)(Hh << icShift) * 8192;
  const short* qb = P + (size_t)(h * IC + ii) * 8192 + half * 4096;
  const short* kb = P + WC + (size_t)(h * IC + ii) * 8192;
  const short* vb = kb + WC;

  f32x4 o[2][2];
#pragma unroll
  for (int tr = 0; tr < 2; ++tr)
#pragma unroll
    for (int tm = 0; tm < 2; ++tm) o[tr][tm] = {0.f, 0.f, 0.f, 0.f};

  for (int chunk = 0; chunk < 2; ++chunk) {
    const int Jb = chunk * 128;
    if (chunk) __syncthreads();           // prior chunk's Ks/Vt/E/cs reads done
#pragma unroll
    for (int u = 0; u < 2; ++u) {         // stage K chunk (8 KB)
      int seg = wv * 2 + u;
      __builtin_amdgcn_global_load_lds(
          (const __attribute__((address_space(1))) void*)(kb + Jb * 32 + seg * 512 + ln * 8),
          (__attribute__((address_space(3))) void*)&lds[KsO + seg * 512], 16, 0, 0);
    }
    if (chunk == 0) {
#pragma unroll
      for (int u = 0; u < 2; ++u) {       // stage Q once
        int seg = wv * 2 + u;
        __builtin_amdgcn_global_load_lds(
            (const __attribute__((address_space(1))) void*)(qb + seg * 512 + ln * 8),
            (__attribute__((address_space(3))) void*)&lds[QsO + seg * 512], 16, 0, 0);
      }
      if (t < 128) denom[t] = 0.f;
    }
#pragma unroll
    for (int u = 0; u < 2; ++u) {         // stage V chunk transposed: Vt[m][Jl]
      int idx = t + u * 256;
      int Jl = idx >> 2, m0 = (idx & 3) * 8;
      uint4 v = *(const uint4*)(vb + Jb * 32 + idx * 8);
      const short* vs = (const short*)&v;
#pragma unroll
      for (int q = 0; q < 8; ++q) lds[VtO + (m0 + q) * 136 + Jl] = vs[q];
    }
    __syncthreads();

    // S^T-MFMA: rows J (wr*64), cols j (wc*64)
    short8 af[4], bf[4];
#pragma unroll
    for (int ti = 0; ti < 4; ++ti)
      af[ti] = *(const short8*)&lds[KsO + (wr * 64 + ti * 16 + lr) * 32 + kq * 8];
#pragma unroll
    for (int tj = 0; tj < 4; ++tj)
      bf[tj] = *(const short8*)&lds[QsO + (wc * 64 + tj * 16 + lr) * 32 + kq * 8];
    f32x4 e[4][4];
#pragma unroll
    for (int ti = 0; ti < 4; ++ti)
#pragma unroll
      for (int tj = 0; tj < 4; ++tj) e[ti][tj] = {0.f, 0.f, 0.f, 0.f};
#pragma unroll
    for (int ti = 0; ti < 4; ++ti)
#pragma unroll
      for (int tj = 0; tj < 4; ++tj)
        e[ti][tj] = __builtin_amdgcn_mfma_f32_16x16x32_bf16(af[ti], bf[tj], e[ti][tj], 0, 0, 0);

    // exp + per-col (query j) partial sums over this wave's 64 J-rows
    float cp[4] = {0.f, 0.f, 0.f, 0.f};
#pragma unroll
    for (int ti = 0; ti < 4; ++ti)
#pragma unroll
      for (int tj = 0; tj < 4; ++tj)
#pragma unroll
        for (int r = 0; r < 4; ++r) {
          float ex = __expf(e[ti][tj][r]);
          e[ti][tj][r] = ex;
          cp[tj] += ex;
        }
#pragma unroll
    for (int tj = 0; tj < 4; ++tj) {
      cp[tj] += __shfl_xor(cp[tj], 16, 64);
      cp[tj] += __shfl_xor(cp[tj], 32, 64);
    }
    if (kq == 0) {
#pragma unroll
      for (int tj = 0; tj < 4; ++tj)
        cs[wr * 128 + wc * 64 + tj * 16 + lr] = cp[tj];
    }
    // write E[j][Jl] (b64 per tile)
#pragma unroll
    for (int ti = 0; ti < 4; ++ti)
#pragma unroll
      for (int tj = 0; tj < 4; ++tj) {
        int j  = wc * 64 + tj * 16 + lr;
        int Jl = wr * 64 + ti * 16 + kq * 4;
        uint2 pk;
        pk.x = pk2(e[ti][tj][0], e[ti][tj][1]);
        pk.y = pk2(e[ti][tj][2], e[ti][tj][3]);
        *(uint2*)&lds[EO + j * 136 + Jl] = pk;
      }
    __syncthreads();
    if (t < 128) denom[t] += cs[t] + cs[128 + t];

    // PV accumulate: D[j][m] += sum_Jl E[j][Jl] Vt[m][Jl]
#pragma unroll
    for (int ks = 0; ks < 4; ++ks) {
      short8 ea[2], vf[2];
#pragma unroll
      for (int tr = 0; tr < 2; ++tr)
        ea[tr] = *(const short8*)&lds[EO + (wv * 32 + tr * 16 + lr) * 136 + ks * 32 + kq * 8];
#pragma unroll
      for (int tm = 0; tm < 2; ++tm)
        vf[tm] = *(const short8*)&lds[VtO + (tm * 16 + lr) * 136 + ks * 32 + kq * 8];
#pragma unroll
      for (int tr = 0; tr < 2; ++tr)
#pragma unroll
        for (int tm = 0; tm < 2; ++tm)
          o[tr][tm] = __builtin_amdgcn_mfma_f32_16x16x32_bf16(ea[tr], vf[tm], o[tr][tm], 0, 0, 0);
    }
  }
  __syncthreads();   // denom final; all LDS reads done

  // normalize + O -> LDS (alias Qs/Ks, dead) -> coalesced store
#pragma unroll
  for (int tr = 0; tr < 2; ++tr)
#pragma unroll
    for (int r = 0; r < 4; ++r) {
      int row = wv * 32 + tr * 16 + kq * 4 + r;
      float rinv = 1.f / denom[row];
#pragma unroll
      for (int tm = 0; tm < 2; ++tm)
        lds[row * 40 + tm * 16 + lr] = (short)f2bf(o[tr][tm][r] * rinv);
    }
  __syncthreads();
#pragma unroll
  for (int u = 0; u < 2; ++u) {
    int idx = t + u * 256;
    int jl = idx >> 2, mg = idx & 3;
    uint4 vv = *(const uint4*)&lds[jl * 40 + mg * 8];
    *(uint4*)(PA + ((size_t)(ii * Pp + half * 128 + jl) * OUTC + h * 32 + mg * 8)) = vv;
  }
}

// ---------------------------------------------------------------------------
extern "C" void kernel_launch(void* const* d_in, const int* in_sizes, int n_in,
                              void* d_out, int out_size, void* d_ws, size_t ws_size,
                              hipStream_t stream) {
  const float* x  = (const float*)d_in[0];
  const float* Wt = (const float*)d_in[1];
  const float* Wp = (const float*)d_in[2];
  const float* W1 = (const float*)d_in[3];
  const float* b1 = (const float*)d_in[4];
  const float* W2 = (const float*)d_in[5];
  const float* b2 = (const float*)d_in[6];
  float* out = (float*)d_out;
  short* ws  = (short*)d_ws;

  const size_t fixedH = 8388608 + 16777216 + 393216 + 786432 + 1048576 + 1048576;
  size_t availH = ws_size / 2;
  size_t chF; int RM, JC, IC;
  if      (availH >= fixedH + 67108864) { chF = 67108864; RM = 32768; JC = 64; IC = 32; }
  else if (availH >= fixedH + 16777216) { chF = 16777216; RM = 8192;  JC = 64; IC = 32; }
  else if (availH >= fixedH + 8388608)  { chF = 8388608;  RM = 4096;  JC = 32; IC = 16; }
  else                                  { chF = 4194304;  RM = 2048;  JC = 16; IC = 8;  }
  short* CH  = ws;
  short* xbf = CH + chF;
  short* At  = xbf + 8388608;
  short* B1t = At + 16777216;
  short* B2t = B1t + 393216;
  short* W1t = B2t + 786432;
  short* W2t = W1t + 1048576;
  const int jcS = __builtin_ctz((unsigned)JC);
  const int icS = __builtin_ctz((unsigned)IC);

  conv_x<<<4096, 256, 0, stream>>>(x, xbf);
  repack_b1t<<<1536, 256, 0, stream>>>(Wt, B1t);
  repack_b2t<<<3072, 256, 0, stream>>>(Wp, B2t);
  repack_w1t<<<4096, 256, 0, stream>>>(W1, W1t);
  repack_w2t<<<4096, 256, 0, stream>>>(W2, W2t);

  for (int j0 = 0; j0 < Pp; j0 += JC) {
    gemm_mfma<256, 1536, 1, 1, 0><<<dim3(12, JC), 256, 0, stream>>>(xbf, B1t, CH, nullptr, j0, jcS, JC);
    temporal_attn_mfma<<<Hh * JC, 256, 0, stream>>>(CH, At, j0, jcS);
  }
  for (int i0 = 0; i0 < Nf; i0 += IC) {
    short* Arows = At + (size_t)i0 * Pp * OUTC;
    gemm_mfma<512, 1536, 0, 2, 0><<<dim3(12, IC * 2), 256, 0, stream>>>(Arows, B2t, CH, nullptr, 0, 0, IC);
    point_attn_mfma<<<Hh * IC * 2, 256, 0, stream>>>(CH, Arows, icS);
  }
  for (int r0 = 0; r0 < Nf * Pp; r0 += RM) {
    gemm_mfma<512, 2048, 0, 0, 0><<<dim3(16, RM / 128), 256, 0, stream>>>(At + (size_t)r0 * OUTC, W1t, CH, b1, 0, 0, 0);
    gemm_mfma<2048, 512, 0, 0, 1><<<dim3(4, RM / 128), 256, 0, stream>>>(CH, W2t, out + (size_t)r0 * OUTC, b2, 0, 0, 0);
  }
}

// Round 5
// 530.955 us; speedup vs baseline: 7.2400x; 1.1504x over previous
//
#include <hip/hip_runtime.h>
#include <cstddef>
#include <cstdint>

constexpr int Nf = 128, Pp = 256, Dd = 256, Hh = 16, Mm = 32;
constexpr int OUTC = 512, HID = 2048, C3 = 1536;

typedef short short8 __attribute__((ext_vector_type(8)));   // 8 bf16 (4 VGPRs)
typedef float f32x4 __attribute__((ext_vector_type(4)));    // 4 fp32 acc

// fp32 -> bf16 round-to-nearest-even
__device__ inline unsigned short f2bf(float f) {
  unsigned u = __float_as_uint(f);
  u += 0x7fffu + ((u >> 16) & 1u);
  return (unsigned short)(u >> 16);
}
__device__ inline unsigned pk2(float a, float b) {
  return (unsigned)f2bf(a) | ((unsigned)f2bf(b) << 16);
}

// ---------------------------------------------------------------------------
__global__ __launch_bounds__(256) void conv_x(const float* __restrict__ x,
                                              short* __restrict__ xb) {
  int idx = blockIdx.x * 256 + threadIdx.x;
  const float4* s = (const float4*)x + (size_t)idx * 2;
  float4 a = s[0], c = s[1];
  uint4 o;
  o.x = pk2(a.x, a.y); o.y = pk2(a.z, a.w);
  o.z = pk2(c.x, c.y); o.w = pk2(c.z, c.w);
  ((uint4*)xb)[idx] = o;
}

// Generic coalesced transpose: in (R x C fp32, slice z) -> out (C x R bf16).
// 64x64 tiles, LDS stride 65 (write phase 2-way conflicts only).
__global__ __launch_bounds__(256) void transpose_to_bf16(const float* __restrict__ in,
                                                         short* __restrict__ out,
                                                         int R, int C) {
  __shared__ float tile[64 * 65];
  const int t = threadIdx.x;
  const int rb = blockIdx.y * 64, cb = blockIdx.x * 64;
  const size_t sl = (size_t)blockIdx.z * R * C;
#pragma unroll
  for (int u = 0; u < 4; ++u) {
    int r = (t >> 4) + u * 16, c4 = (t & 15) * 4;
    float4 v = *(const float4*)(in + sl + (size_t)(rb + r) * C + cb + c4);
    tile[r * 65 + c4 + 0] = v.x;
    tile[r * 65 + c4 + 1] = v.y;
    tile[r * 65 + c4 + 2] = v.z;
    tile[r * 65 + c4 + 3] = v.w;
  }
  __syncthreads();
#pragma unroll
  for (int u = 0; u < 2; ++u) {
    int id = t + u * 256;
    int n = id >> 3, kg = id & 7;
    float a[8];
#pragma unroll
    for (int q = 0; q < 8; ++q) a[q] = tile[(kg * 8 + q) * 65 + n];
    uint4 o;
    o.x = pk2(a[0], a[1]); o.y = pk2(a[2], a[3]);
    o.z = pk2(a[4], a[5]); o.w = pk2(a[6], a[7]);
    *(uint4*)(out + sl + (size_t)(cb + n) * R + rb + kg * 8) = o;
  }
}

// B2t[c][k], k = HH*32+MM (1536 x 512) — reads are 128B runs, already coalesced.
__global__ void repack_b2t(const float* __restrict__ Wp, short* __restrict__ B2t) {
  int idx = blockIdx.x * 256 + threadIdx.x;  // 786432
  int c = idx >> 9, k = idx & 511;
  int w = c >> 9, h = (c >> 5) & 15, m = c & 31;
  int HH = k >> 5, MM = k & 31;
  B2t[idx] = (short)f2bf(Wp[(((w * Hh + h) * Mm + m) * Hh + HH) * Mm + MM]);
}

// ---------------------------------------------------------------------------
// bf16 MFMA GEMM (m97 structure) + XCD-aware block swizzle: all col-blocks
// sharing an A row-panel land on the SAME XCD in consecutive dispatch slots,
// so A re-reads hit that XCD's L2 instead of HBM.
template <int KDIM, int NCOLS, int AMAP, int EPI, int OUTT>
__global__ __launch_bounds__(256) void gemm_mfma(const short* __restrict__ A,
                                                 const short* __restrict__ Bt,
                                                 void* __restrict__ Cv,
                                                 const float* __restrict__ bias,
                                                 int j0, int pshift, int pc) {
  __shared__ short As[128 * 32];
  __shared__ short Bs[128 * 32];
  const int t = threadIdx.x;
  const int wv = t >> 6, ln = t & 63;
  const int wr = wv >> 1, wc = wv & 1;
  const int lr = ln & 15, kq = ln >> 4;

  constexpr int NBX = NCOLS / 128;
  int lin = blockIdx.y * NBX + blockIdx.x;
  int nblk = gridDim.x * gridDim.y;
  int bx, by;
  if ((nblk & 7) == 0) {
    int per = nblk >> 3;
    int id = (lin & 7) * per + (lin >> 3);   // bijective; groups rows per XCD
    bx = id % NBX; by = id / NBX;
  } else {
    bx = blockIdx.x; by = blockIdx.y;
  }
  const int row0 = by * 128, col0 = bx * 128;

  f32x4 acc[4][4];
#pragma unroll
  for (int i = 0; i < 4; ++i)
#pragma unroll
    for (int j = 0; j < 4; ++j) acc[i][j] = {0.f, 0.f, 0.f, 0.f};

  for (int kt = 0; kt < KDIM; kt += 32) {
#pragma unroll
    for (int u = 0; u < 2; ++u) {
      int seg = wv * 128 + u * 64 + ln;
      int r = seg >> 2, kg = seg & 3;
      int rr = row0 + r;
      size_t arow;
      if (AMAP == 0) arow = (size_t)rr;
      else { int i = rr >> pshift, jj = rr & (pc - 1); arow = (size_t)((i << 8) + j0 + jj); }
      const short* gp = A + arow * KDIM + kt + kg * 8;
      __builtin_amdgcn_global_load_lds(
          (const __attribute__((address_space(1))) void*)gp,
          (__attribute__((address_space(3))) void*)&As[(wv * 128 + u * 64) * 8], 16, 0, 0);
    }
#pragma unroll
    for (int u = 0; u < 2; ++u) {
      int seg = wv * 128 + u * 64 + ln;
      int r = seg >> 2, kg = seg & 3;
      const short* gp = Bt + (size_t)(col0 + r) * KDIM + kt + kg * 8;
      __builtin_amdgcn_global_load_lds(
          (const __attribute__((address_space(1))) void*)gp,
          (__attribute__((address_space(3))) void*)&Bs[(wv * 128 + u * 64) * 8], 16, 0, 0);
    }
    __syncthreads();
    short8 a[4], b[4];
#pragma unroll
    for (int ti = 0; ti < 4; ++ti)
      a[ti] = *(const short8*)&As[(wr * 64 + ti * 16 + lr) * 32 + kq * 8];
#pragma unroll
    for (int tj = 0; tj < 4; ++tj)
      b[tj] = *(const short8*)&Bs[(wc * 64 + tj * 16 + lr) * 32 + kq * 8];
#pragma unroll
    for (int ti = 0; ti < 4; ++ti)
#pragma unroll
      for (int tj = 0; tj < 4; ++tj)
        acc[ti][tj] = __builtin_amdgcn_mfma_f32_16x16x32_bf16(a[ti], b[tj], acc[ti][tj], 0, 0, 0);
    __syncthreads();
  }

#pragma unroll
  for (int tj = 0; tj < 4; ++tj) {
    int gcol = col0 + wc * 64 + tj * 16 + lr;
    float bv = (EPI == 0) ? bias[gcol] : 0.f;
#pragma unroll
    for (int ti = 0; ti < 4; ++ti) {
#pragma unroll
      for (int rg = 0; rg < 4; ++rg) {
        int grow = row0 + wr * 64 + ti * 16 + kq * 4 + rg;
        float val = acc[ti][tj][rg];
        if (EPI == 0) {
          val += bv;
          if (OUTT == 0) ((short*)Cv)[(size_t)grow * NCOLS + gcol] = (short)f2bf(val);
          else           ((float*)Cv)[(size_t)grow * NCOLS + gcol] = val;
        } else {
          int w = gcol >> 9, h = (gcol >> 5) & 15, m = gcol & 31;
          size_t addr;
          if (EPI == 1) {
            int i = grow >> pshift, jj = grow & (pc - 1);
            addr = (((size_t)(w * Hh + h) * pc + jj) * Nf + i) * Mm + m;
          } else {
            int ii = grow >> 8, j = grow & 255;
            addr = (((size_t)(w * Hh + h) * pc + ii) * Pp + j) * Mm + m;
          }
          ((short*)Cv)[addr] = (short)f2bf(val);
        }
      }
    }
  }
}

// ---------------------------------------------------------------------------
// Temporal attention, MFMA (unchanged from round 4 — verified).
__global__ __launch_bounds__(256) void temporal_attn_mfma(const short* __restrict__ T,
                                                          short* __restrict__ At,
                                                          int j0, int jcShift) {
  constexpr int QsO = 0, KsO = 4096, VtO = 8192, WtO = 12544, RsO = 29952;
  __shared__ __align__(16) short lds[30464];
  float* rs = (float*)&lds[RsO];
  const int JC = 1 << jcShift;
  const int h  = blockIdx.x >> jcShift;
  const int jj = blockIdx.x & (JC - 1);
  const int t  = threadIdx.x;
  const int wv = t >> 6, ln = t & 63;
  const int wr = wv >> 1, wc = wv & 1;
  const int lr = ln & 15, kq = ln >> 4;
  const size_t WC = (size_t)(Hh << jcShift) * 4096;
  const short* qb = T + (size_t)(h * JC + jj) * 4096;
  const short* kb = qb + WC;
  const short* vb = qb + 2 * WC;

#pragma unroll
  for (int u = 0; u < 2; ++u) {
    int seg = wv * 2 + u;
    __builtin_amdgcn_global_load_lds(
        (const __attribute__((address_space(1))) void*)(qb + seg * 512 + ln * 8),
        (__attribute__((address_space(3))) void*)&lds[QsO + seg * 512], 16, 0, 0);
    __builtin_amdgcn_global_load_lds(
        (const __attribute__((address_space(1))) void*)(kb + seg * 512 + ln * 8),
        (__attribute__((address_space(3))) void*)&lds[KsO + seg * 512], 16, 0, 0);
  }
#pragma unroll
  for (int u = 0; u < 2; ++u) {
    int idx = t + u * 256;
    int I = idx >> 2, m0 = (idx & 3) * 8;
    uint4 v = *(const uint4*)(vb + idx * 8);
    const short* vs = (const short*)&v;
#pragma unroll
    for (int q = 0; q < 8; ++q) lds[VtO + (m0 + q) * 136 + I] = vs[q];
  }
  __syncthreads();

  short8 af[4], bf[4];
#pragma unroll
  for (int ti = 0; ti < 4; ++ti)
    af[ti] = *(const short8*)&lds[QsO + (wr * 64 + ti * 16 + lr) * 32 + kq * 8];
#pragma unroll
  for (int tj = 0; tj < 4; ++tj)
    bf[tj] = *(const short8*)&lds[KsO + (wc * 64 + tj * 16 + lr) * 32 + kq * 8];
  f32x4 e[4][4];
#pragma unroll
  for (int ti = 0; ti < 4; ++ti)
#pragma unroll
    for (int tj = 0; tj < 4; ++tj) e[ti][tj] = {0.f, 0.f, 0.f, 0.f};
#pragma unroll
  for (int ti = 0; ti < 4; ++ti)
#pragma unroll
    for (int tj = 0; tj < 4; ++tj)
      e[ti][tj] = __builtin_amdgcn_mfma_f32_16x16x32_bf16(af[ti], bf[tj], e[ti][tj], 0, 0, 0);

  float part[4][4];
#pragma unroll
  for (int ti = 0; ti < 4; ++ti)
#pragma unroll
    for (int r = 0; r < 4; ++r) {
      float p = 0.f;
#pragma unroll
      for (int tj = 0; tj < 4; ++tj) {
        float ex = __expf(e[ti][tj][r]);
        e[ti][tj][r] = ex;
        p += ex;
      }
      part[ti][r] = p;
    }
#pragma unroll
  for (int msk = 1; msk <= 8; msk <<= 1)
#pragma unroll
    for (int ti = 0; ti < 4; ++ti)
#pragma unroll
      for (int r = 0; r < 4; ++r)
        part[ti][r] += __shfl_xor(part[ti][r], msk, 64);
  if (lr == 0) {
#pragma unroll
    for (int ti = 0; ti < 4; ++ti)
#pragma unroll
      for (int r = 0; r < 4; ++r)
        rs[wc * 128 + wr * 64 + ti * 16 + kq * 4 + r] = part[ti][r];
  }
  __syncthreads();

#pragma unroll
  for (int ti = 0; ti < 4; ++ti) {
#pragma unroll
    for (int r = 0; r < 4; ++r) {
      int I = wr * 64 + ti * 16 + kq * 4 + r;
      float inv = 1.f / (rs[I] + rs[128 + I]);
#pragma unroll
      for (int tj = 0; tj < 4; ++tj) e[ti][tj][r] *= inv;
    }
#pragma unroll
    for (int tj = 0; tj < 4; ++tj) {
      int i = wc * 64 + tj * 16 + lr;
      int Ib = wr * 64 + ti * 16 + kq * 4;
      uint2 pk;
      pk.x = pk2(e[ti][tj][0], e[ti][tj][1]);
      pk.y = pk2(e[ti][tj][2], e[ti][tj][3]);
      *(uint2*)&lds[WtO + i * 136 + Ib] = pk;
    }
  }
  __syncthreads();

  f32x4 o[2][2];
#pragma unroll
  for (int tr = 0; tr < 2; ++tr)
#pragma unroll
    for (int tm = 0; tm < 2; ++tm) o[tr][tm] = {0.f, 0.f, 0.f, 0.f};
#pragma unroll
  for (int ks = 0; ks < 4; ++ks) {
    short8 ea[2], vf[2];
#pragma unroll
    for (int tr = 0; tr < 2; ++tr)
      ea[tr] = *(const short8*)&lds[WtO + (wv * 32 + tr * 16 + lr) * 136 + ks * 32 + kq * 8];
#pragma unroll
    for (int tm = 0; tm < 2; ++tm)
      vf[tm] = *(const short8*)&lds[VtO + (tm * 16 + lr) * 136 + ks * 32 + kq * 8];
#pragma unroll
    for (int tr = 0; tr < 2; ++tr)
#pragma unroll
      for (int tm = 0; tm < 2; ++tm)
        o[tr][tm] = __builtin_amdgcn_mfma_f32_16x16x32_bf16(ea[tr], vf[tm], o[tr][tm], 0, 0, 0);
  }
#pragma unroll
  for (int tr = 0; tr < 2; ++tr)
#pragma unroll
    for (int tm = 0; tm < 2; ++tm)
#pragma unroll
      for (int r = 0; r < 4; ++r) {
        int row = wv * 32 + tr * 16 + kq * 4 + r;
        lds[row * 40 + tm * 16 + lr] = (short)f2bf(o[tr][tm][r]);
      }
  __syncthreads();
#pragma unroll
  for (int u = 0; u < 2; ++u) {
    int idx = t + u * 256;
    int i = idx >> 2, mg = idx & 3;
    uint4 vv = *(const uint4*)&lds[i * 40 + mg * 8];
    *(uint4*)(At + ((size_t)(i * Pp + j0 + jj) * OUTC + h * 32 + mg * 8)) = vv;
  }
}

// ---------------------------------------------------------------------------
// Point attention, MFMA (unchanged from round 4 — verified).
__global__ __launch_bounds__(256) void point_attn_mfma(const short* __restrict__ P,
                                                       short* __restrict__ PA,
                                                       int icShift) {
  constexpr int QsO = 0, KsO = 4096, VtO = 8192, EO = 12544, CsO = 29952;
  __shared__ __align__(16) short lds[30720];
  float* cs    = (float*)&lds[CsO];
  float* denom = cs + 256;
  const int IC = 1 << icShift;
  const int bx = blockIdx.x;
  const int h    = bx >> (icShift + 1);
  const int rem  = bx & ((IC << 1) - 1);
  const int ii   = rem >> 1;
  const int half = rem & 1;
  const int t  = threadIdx.x;
  const int wv = t >> 6, ln = t & 63;
  const int wr = wv >> 1, wc = wv & 1;
  const int lr = ln & 15, kq = ln >> 4;
  const size_t WC = (size_t)(Hh << icShift) * 8192;
  const short* qb = P + (size_t)(h * IC + ii) * 8192 + half * 4096;
  const short* kb = P + WC + (size_t)(h * IC + ii) * 8192;
  const short* vb = kb + WC;

  f32x4 o[2][2];
#pragma unroll
  for (int tr = 0; tr < 2; ++tr)
#pragma unroll
    for (int tm = 0; tm < 2; ++tm) o[tr][tm] = {0.f, 0.f, 0.f, 0.f};

  for (int chunk = 0; chunk < 2; ++chunk) {
    const int Jb = chunk * 128;
    if (chunk) __syncthreads();
#pragma unroll
    for (int u = 0; u < 2; ++u) {
      int seg = wv * 2 + u;
      __builtin_amdgcn_global_load_lds(
          (const __attribute__((address_space(1))) void*)(kb + Jb * 32 + seg * 512 + ln * 8),
          (__attribute__((address_space(3))) void*)&lds[KsO + seg * 512], 16, 0, 0);
    }
    if (chunk == 0) {
#pragma unroll
      for (int u = 0; u < 2; ++u) {
        int seg = wv * 2 + u;
        __builtin_amdgcn_global_load_lds(
            (const __attribute__((address_space(1))) void*)(qb + seg * 512 + ln * 8),
            (__attribute__((address_space(3))) void*)&lds[QsO + seg * 512], 16, 0, 0);
      }
      if (t < 128) denom[t] = 0.f;
    }
#pragma unroll
    for (int u = 0; u < 2; ++u) {
      int idx = t + u * 256;
      int Jl = idx >> 2, m0 = (idx & 3) * 8;
      uint4 v = *(const uint4*)(vb + Jb * 32 + idx * 8);
      const short* vs = (const short*)&v;
#pragma unroll
      for (int q = 0; q < 8; ++q) lds[VtO + (m0 + q) * 136 + Jl] = vs[q];
    }
    __syncthreads();

    short8 af[4], bf[4];
#pragma unroll
    for (int ti = 0; ti < 4; ++ti)
      af[ti] = *(const short8*)&lds[KsO + (wr * 64 + ti * 16 + lr) * 32 + kq * 8];
#pragma unroll
    for (int tj = 0; tj < 4; ++tj)
      bf[tj] = *(const short8*)&lds[QsO + (wc * 64 + tj * 16 + lr) * 32 + kq * 8];
    f32x4 e[4][4];
#pragma unroll
    for (int ti = 0; ti < 4; ++ti)
#pragma unroll
      for (int tj = 0; tj < 4; ++tj) e[ti][tj] = {0.f, 0.f, 0.f, 0.f};
#pragma unroll
    for (int ti = 0; ti < 4; ++ti)
#pragma unroll
      for (int tj = 0; tj < 4; ++tj)
        e[ti][tj] = __builtin_amdgcn_mfma_f32_16x16x32_bf16(af[ti], bf[tj], e[ti][tj], 0, 0, 0);

    float cp[4] = {0.f, 0.f, 0.f, 0.f};
#pragma unroll
    for (int ti = 0; ti < 4; ++ti)
#pragma unroll
      for (int tj = 0; tj < 4; ++tj)
#pragma unroll
        for (int r = 0; r < 4; ++r) {
          float ex = __expf(e[ti][tj][r]);
          e[ti][tj][r] = ex;
          cp[tj] += ex;
        }
#pragma unroll
    for (int tj = 0; tj < 4; ++tj) {
      cp[tj] += __shfl_xor(cp[tj], 16, 64);
      cp[tj] += __shfl_xor(cp[tj], 32, 64);
    }
    if (kq == 0) {
#pragma unroll
      for (int tj = 0; tj < 4; ++tj)
        cs[wr * 128 + wc * 64 + tj * 16 + lr] = cp[tj];
    }
#pragma unroll
    for (int ti = 0; ti < 4; ++ti)
#pragma unroll
      for (int tj = 0; tj < 4; ++tj) {
        int j  = wc * 64 + tj * 16 + lr;
        int Jl = wr * 64 + ti * 16 + kq * 4;
        uint2 pk;
        pk.x = pk2(e[ti][tj][0], e[ti][tj][1]);
        pk.y = pk2(e[ti][tj][2], e[ti][tj][3]);
        *(uint2*)&lds[EO + j * 136 + Jl] = pk;
      }
    __syncthreads();
    if (t < 128) denom[t] += cs[t] + cs[128 + t];

#pragma unroll
    for (int ks = 0; ks < 4; ++ks) {
      short8 ea[2], vf[2];
#pragma unroll
      for (int tr = 0; tr < 2; ++tr)
        ea[tr] = *(const short8*)&lds[EO + (wv * 32 + tr * 16 + lr) * 136 + ks * 32 + kq * 8];
#pragma unroll
      for (int tm = 0; tm < 2; ++tm)
        vf[tm] = *(const short8*)&lds[VtO + (tm * 16 + lr) * 136 + ks * 32 + kq * 8];
#pragma unroll
      for (int tr = 0; tr < 2; ++tr)
#pragma unroll
        for (int tm = 0; tm < 2; ++tm)
          o[tr][tm] = __builtin_amdgcn_mfma_f32_16x16x32_bf16(ea[tr], vf[tm], o[tr][tm], 0, 0, 0);
    }
  }
  __syncthreads();

#pragma unroll
  for (int tr = 0; tr < 2; ++tr)
#pragma unroll
    for (int r = 0; r < 4; ++r) {
      int row = wv * 32 + tr * 16 + kq * 4 + r;
      float rinv = 1.f / denom[row];
#pragma unroll
      for (int tm = 0; tm < 2; ++tm)
        lds[row * 40 + tm * 16 + lr] = (short)f2bf(o[tr][tm][r] * rinv);
    }
  __syncthreads();
#pragma unroll
  for (int u = 0; u < 2; ++u) {
    int idx = t + u * 256;
    int jl = idx >> 2, mg = idx & 3;
    uint4 vv = *(const uint4*)&lds[jl * 40 + mg * 8];
    *(uint4*)(PA + ((size_t)(ii * Pp + half * 128 + jl) * OUTC + h * 32 + mg * 8)) = vv;
  }
}

// ---------------------------------------------------------------------------
extern "C" void kernel_launch(void* const* d_in, const int* in_sizes, int n_in,
                              void* d_out, int out_size, void* d_ws, size_t ws_size,
                              hipStream_t stream) {
  const float* x  = (const float*)d_in[0];
  const float* Wt = (const float*)d_in[1];
  const float* Wp = (const float*)d_in[2];
  const float* W1 = (const float*)d_in[3];
  const float* b1 = (const float*)d_in[4];
  const float* W2 = (const float*)d_in[5];
  const float* b2 = (const float*)d_in[6];
  float* out = (float*)d_out;
  short* ws  = (short*)d_ws;

  const size_t fixedH = 8388608 + 16777216 + 393216 + 786432 + 1048576 + 1048576;
  size_t availH = ws_size / 2;
  size_t chF; int RM, JC, IC;
  if      (availH >= fixedH + 67108864) { chF = 67108864; RM = 32768; JC = 256; IC = 128; }
  else if (availH >= fixedH + 16777216) { chF = 16777216; RM = 8192;  JC = 64;  IC = 32;  }
  else if (availH >= fixedH + 8388608)  { chF = 8388608;  RM = 4096;  JC = 32;  IC = 16;  }
  else                                  { chF = 4194304;  RM = 2048;  JC = 16;  IC = 8;   }
  short* CH  = ws;
  short* xbf = CH + chF;
  short* At  = xbf + 8388608;
  short* B1t = At + 16777216;
  short* B2t = B1t + 393216;
  short* W1t = B2t + 786432;
  short* W2t = W1t + 1048576;
  const int jcS = __builtin_ctz((unsigned)JC);
  const int icS = __builtin_ctz((unsigned)IC);

  conv_x<<<4096, 256, 0, stream>>>(x, xbf);
  // Wt (3,256,16,32): per-w transpose of in[d][hm] (256x512) -> B1t[hm][d]
  transpose_to_bf16<<<dim3(8, 4, 3), 256, 0, stream>>>(Wt, B1t, 256, 512);
  repack_b2t<<<3072, 256, 0, stream>>>(Wp, B2t);
  transpose_to_bf16<<<dim3(32, 8, 1), 256, 0, stream>>>(W1, W1t, 512, 2048);
  transpose_to_bf16<<<dim3(8, 32, 1), 256, 0, stream>>>(W2, W2t, 2048, 512);

  if (JC == 256) {
    // Full-size pipeline: 6 fat launches.
    gemm_mfma<256, 1536, 0, 1, 0><<<dim3(12, 256), 256, 0, stream>>>(xbf, B1t, CH, nullptr, 0, 8, 256);
    temporal_attn_mfma<<<Hh * 256, 256, 0, stream>>>(CH, At, 0, 8);
    gemm_mfma<512, 1536, 0, 2, 0><<<dim3(12, 256), 256, 0, stream>>>(At, B2t, CH, nullptr, 0, 0, 128);
    point_attn_mfma<<<Hh * 128 * 2, 256, 0, stream>>>(CH, At, 7);
    gemm_mfma<512, 2048, 0, 0, 0><<<dim3(16, 256), 256, 0, stream>>>(At, W1t, CH, b1, 0, 0, 0);
    gemm_mfma<2048, 512, 0, 0, 1><<<dim3(4, 256), 256, 0, stream>>>(CH, W2t, out, b2, 0, 0, 0);
  } else {
    for (int j0 = 0; j0 < Pp; j0 += JC) {
      gemm_mfma<256, 1536, 1, 1, 0><<<dim3(12, JC), 256, 0, stream>>>(xbf, B1t, CH, nullptr, j0, jcS, JC);
      temporal_attn_mfma<<<Hh * JC, 256, 0, stream>>>(CH, At, j0, jcS);
    }
    for (int i0 = 0; i0 < Nf; i0 += IC) {
      short* Arows = At + (size_t)i0 * Pp * OUTC;
      gemm_mfma<512, 1536, 0, 2, 0><<<dim3(12, IC * 2), 256, 0, stream>>>(Arows, B2t, CH, nullptr, 0, 0, IC);
      point_attn_mfma<<<Hh * IC * 2, 256, 0, stream>>>(CH, Arows, icS);
    }
    for (int r0 = 0; r0 < Nf * Pp; r0 += RM) {
      gemm_mfma<512, 2048, 0, 0, 0><<<dim3(16, RM / 128), 256, 0, stream>>>(At + (size_t)r0 * OUTC, W1t, CH, b1, 0, 0, 0);
      gemm_mfma<2048, 512, 0, 0, 1><<<dim3(4, RM / 128), 256, 0, stream>>>(CH, W2t, out + (size_t)r0 * OUTC, b2, 0, 0, 0);
    }
  }
}